// Round 1
// baseline (342.854 us; speedup 1.0000x reference)
//
#include <hip/hip_runtime.h>
#include <math.h>

// SSIM loss fp32, B=64 H=W=512, 11x11 Gaussian sigma=1.5, separable (w ⊗ w).
// R9: latency-bound fix. R8 counters: VALUBusy 30%, HBM 16%, Occupancy 23%
// (~7.5 waves/CU effective) -> stall-bound. VGPR_Count=52 proved the R8 load
// batching never made it into the binary (20 float4 = 80 VGPRs can't fly in
// 52). Changes:
//  - v2f lanes repacked (row,row+32) -> (col c, col c+16): LDS 43008->37888B,
//    74 unique h-rows stored/computed once (was 84).
//  - __launch_bounds__(512,4): ~128 VGPR budget so batched loads are real.
//  - stage2: 296 single-row tasks, 18 contiguous f4 each (was 336x20).
//  - stage3: per-quantity 6xb128 (aligned, even bank spread at stride 74 v2f),
//    vertical conv on reg-pair-aligned v2f -> v_pk_fma eligible.

typedef float v2f __attribute__((ext_vector_type(2)));

#define GX 16
#define GY 8
#define NPART (64 * GY * GX)   // 8192

struct W11 { float w[11]; };

__global__ __launch_bounds__(512, 4) void ssim_main(
    const float* __restrict__ x, const float* __restrict__ y,
    float* __restrict__ partial, W11 wk, int atomic_mode)
{
    // hst[q][cp*74 + r]: v2f = (col ox+cp, col ox+cp+16), r in 0..73 maps to
    // input row oy-5+r. 4 * 16*74 * 8B = 37888 B.
    __shared__ __align__(16) v2f hst[4][16 * 74];
    __shared__ float red[8];

    const int tid = threadIdx.x;
    const int bx = blockIdx.x, by = blockIdx.y, bz = blockIdx.z;
    const float* __restrict__ xb = x + (size_t)bz * (512 * 512);
    const float* __restrict__ yb = y + (size_t)bz * (512 * 512);
    const int ox = bx * 32;   // 32-col tile
    const int oy = by * 64;   // 64-row tile

    // ---- stage 2: horizontal convs of {x, y, x^2+y^2, xy} ----
    // 296 tasks = 74 rows x 4 groups; group g covers output cols
    // {c0..c0+3} U {c0+16..c0+19}, c0 = 4g, packed as 4 v2f (lane1 = +16).
    if (tid < 296) {
        const int r  = tid >> 2;            // 0..73
        const int g  = tid & 3;
        const int c0 = g << 2;
        const int gr = oy - 5 + r;
        const float rm = ((unsigned)gr < 512u) ? 1.f : 0.f;
        const int grc  = min(max(gr, 0), 511);
        const int gc0  = ox + c0 - 8;       // f4-aligned (ox%32==0, c0%4==0)

        // window positions: lane0 cols = fx[3+k], lane1 = fx[19+k], k=0..13
        float fx[36], fy[36];
        if (bx >= 1 && bx <= 14) {
            const float4* px = (const float4*)(xb + grc * 512 + gc0);
            const float4* py = (const float4*)(yb + grc * 512 + gc0);
            float4 X[9], Y[9];
            #pragma unroll
            for (int k = 0; k < 9; ++k) X[k] = px[k];
            #pragma unroll
            for (int k = 0; k < 9; ++k) Y[k] = py[k];
            #pragma unroll
            for (int k = 0; k < 9; ++k) {
                fx[4*k+0] = X[k].x * rm; fx[4*k+1] = X[k].y * rm;
                fx[4*k+2] = X[k].z * rm; fx[4*k+3] = X[k].w * rm;
                fy[4*k+0] = Y[k].x * rm; fy[4*k+1] = Y[k].y * rm;
                fy[4*k+2] = Y[k].z * rm; fy[4*k+3] = Y[k].w * rm;
            }
        } else {
            #pragma unroll
            for (int k = 0; k < 36; ++k) {
                const int gc  = gc0 + k;
                const int gcc = min(max(gc, 0), 511);
                const float cm = ((unsigned)gc < 512u) ? rm : 0.f;
                fx[k] = xb[grc * 512 + gcc] * cm;
                fy[k] = yb[grc * 512 + gcc] * cm;
            }
        }

        v2f acc[4][4];
        #pragma unroll
        for (int q = 0; q < 4; ++q)
            #pragma unroll
            for (int oc = 0; oc < 4; ++oc) acc[q][oc] = (v2f)0.f;

        #pragma unroll
        for (int k = 0; k < 14; ++k) {
            const v2f xv = (v2f){fx[3 + k], fx[19 + k]};
            const v2f yv = (v2f){fy[3 + k], fy[19 + k]};
            const v2f ss = xv * xv + yv * yv;
            const v2f xy = xv * yv;
            #pragma unroll
            for (int oc = 0; oc < 4; ++oc) {
                const int j = k - oc;          // compile-time
                if (j < 0 || j > 10) continue;
                const float wj = wk.w[j];
                acc[0][oc] += wj * xv;
                acc[1][oc] += wj * yv;
                acc[2][oc] += wj * ss;
                acc[3][oc] += wj * xy;
            }
        }
        #pragma unroll
        for (int q = 0; q < 4; ++q)
            #pragma unroll
            for (int oc = 0; oc < 4; ++oc)
                hst[q][(c0 + oc) * 74 + r] = acc[q][oc];
    }
    __syncthreads();

    // ---- stage 3: vertical convs + SSIM; 512 threads = 16 cp x 32 row-pairs
    const int cp = tid & 15;
    const int r0 = (tid >> 4) << 1;          // 0..62 even -> 16B aligned
    v2f s[4][2];
    #pragma unroll
    for (int q = 0; q < 4; ++q) {
        const float4* p4 = (const float4*)&hst[q][cp * 74 + r0];
        float4 Q[6];
        #pragma unroll
        for (int k = 0; k < 6; ++k) Q[k] = p4[k];   // rows r0..r0+11 (v2f)
        #pragma unroll
        for (int o = 0; o < 2; ++o) {
            v2f a = (v2f)0.f;
            #pragma unroll
            for (int j = 0; j < 11; ++j) {
                const int t = o + j;                 // compile-time 0..11
                const v2f rv = (t & 1) ? (v2f){Q[t >> 1].z, Q[t >> 1].w}
                                       : (v2f){Q[t >> 1].x, Q[t >> 1].y};
                a += wk.w[j] * rv;
            }
            s[q][o] = a;
        }
    }

    const float C1 = 1e-4f, C2 = 9e-4f;
    float lsum = 0.f;
    #pragma unroll
    for (int o = 0; o < 2; ++o) {
        const v2f mx = s[0][o], my = s[1][o];
        const v2f mx2 = mx * mx, my2 = my * my, mxy = mx * my;
        const v2f sig_sum = s[2][o] - mx2 - my2;   // sigma_x2 + sigma_y2
        const v2f sig_xy  = s[3][o] - mxy;
        const v2f num = (2.f * mxy + C1) * (2.f * sig_xy + C2);
        const v2f den = (mx2 + my2 + C1) * (sig_sum + C2) + 1e-12f;
        lsum += num.x * __builtin_amdgcn_rcpf(den.x)
              + num.y * __builtin_amdgcn_rcpf(den.y);
    }

    // ---- block reduction (8 waves) ----
    #pragma unroll
    for (int off = 32; off; off >>= 1) lsum += __shfl_down(lsum, off);
    if ((tid & 63) == 0) red[tid >> 6] = lsum;
    __syncthreads();
    if (tid == 0) {
        float v = 0.f;
        #pragma unroll
        for (int i = 0; i < 8; ++i) v += red[i];
        if (atomic_mode) atomicAdd(partial, v);
        else partial[(bz * GY + by) * GX + bx] = v;
    }
}

__global__ __launch_bounds__(256) void ssim_fin(const float* __restrict__ partial,
                                                float* __restrict__ out, int n)
{
    float s = 0.f;
    for (int i = threadIdx.x; i < n; i += 256) s += partial[i];
    #pragma unroll
    for (int off = 32; off; off >>= 1) s += __shfl_down(s, off);
    __shared__ float red[4];
    if ((threadIdx.x & 63) == 0) red[threadIdx.x >> 6] = s;
    __syncthreads();
    if (threadIdx.x == 0)
        out[0] = 1.0f - (red[0] + red[1] + red[2] + red[3]) * (1.0f / 16777216.0f);
}

extern "C" void kernel_launch(void* const* d_in, const int* in_sizes, int n_in,
                              void* d_out, int out_size, void* d_ws, size_t ws_size,
                              hipStream_t stream) {
    const float* x = (const float*)d_in[0];
    const float* y = (const float*)d_in[1];
    float* out = (float*)d_out;
    float* ws  = (float*)d_ws;

    W11 wk;
    double e[11], s = 0.0;
    for (int i = 0; i < 11; ++i) {
        double d = (double)i - 5.0;
        e[i] = exp(-(d * d) / 4.5);
        s += e[i];
    }
    for (int i = 0; i < 11; ++i) wk.w[i] = (float)(e[i] / s);

    const bool use_partial = ws_size >= (size_t)NPART * sizeof(float);
    if (!use_partial) hipMemsetAsync(d_ws, 0, sizeof(float), stream);

    hipLaunchKernelGGL(ssim_main, dim3(GX, GY, 64), dim3(512), 0, stream,
                       x, y, ws, wk, use_partial ? 0 : 1);
    hipLaunchKernelGGL(ssim_fin, dim3(1), dim3(256), 0, stream,
                       ws, out, use_partial ? NPART : 1);
}

// Round 2
// 236.745 us; speedup vs baseline: 1.4482x; 1.4482x over previous
//
#include <hip/hip_runtime.h>
#include <math.h>

// SSIM loss fp32, B=64 H=W=512, 11x11 Gaussian sigma=1.5, separable (w ⊗ w).
// R10: structural fix for latency-bound stages. R8/R9 counters proved each
// stage-2 thread's 18-20 global loads serialize into ~900-cycle chains
// (VGPR=52, VALUBusy 17-30%, HBM 10-16%). R10 stages the raw tile through
// LDS once (coalesced, ~4 independent f4 loads/thread), so the h-conv reads
// LDS instead of global. Zero-padding is applied at staging -> stages 2/3
// are branch-free. Tile 32x32, 256 threads, LDS 39 KB -> 4 blocks/CU.
// Stage 3 does 4 rows/thread (vertical re-read traffic -42%).

typedef float v2f __attribute__((ext_vector_type(2)));

#define TSY  32                  // output rows per block
#define HR   42                  // h-rows = TSY + 10
#define RAWS 52                  // raw row stride in floats (48 data + 4 pad)
#define GX   16
#define GY   16
#define NPART (64 * GY * GX)     // 16384

struct W11 { float w[11]; };

__global__ __launch_bounds__(256, 4) void ssim_main(
    const float* __restrict__ x, const float* __restrict__ y,
    float* __restrict__ partial, W11 wk, int atomic_mode)
{
    // raw[a][r][c]: zero-padded input tile, a=0:x a=1:y.
    // raw col c <-> global col ox-8+c, c in 0..47; r <-> global row oy-5+r.
    __shared__ __align__(16) float raw[2][HR][RAWS];        // 17472 B
    // hst[q][cp*HR + r]: v2f = h-conv at (col ox+cp, col ox+cp+16).
    __shared__ __align__(16) v2f hst[4][16 * HR];           // 21504 B
    __shared__ float red[4];

    const int tid = threadIdx.x;
    const int bx = blockIdx.x, by = blockIdx.y, bz = blockIdx.z;
    const float* __restrict__ xb = x + (size_t)bz * (512 * 512);
    const float* __restrict__ yb = y + (size_t)bz * (512 * 512);
    const int ox = bx * 32;
    const int oy = by * TSY;

    // ---- stage 1: coalesced global -> LDS raw staging (zero-padded) ----
    // 1008 float4 tasks = 2 arrays x 42 rows x 12 f4-cols; ~4 per thread,
    // all independent -> one latency window.
    const int NT1 = 2 * HR * 12;             // 1008
    #pragma unroll
    for (int it = 0; it < 4; ++it) {
        const int i = tid + (it << 8);
        if (i < NT1) {
            const int a   = (i >= HR * 12) ? 1 : 0;
            const int j   = i - a * (HR * 12);
            const int row = j / 12;          // 0..41 (magic-mul)
            const int f4c = j - row * 12;    // 0..11
            const int gr  = oy - 5 + row;
            const int gc  = ox - 8 + (f4c << 2);
            const float* __restrict__ sb = a ? yb : xb;
            float4 v = {0.f, 0.f, 0.f, 0.f};
            if ((unsigned)gr < 512u) {
                const float* __restrict__ rp = sb + gr * 512;
                if ((unsigned)gc <= 508u) {  // fast path: uniform for bx 1..14
                    v = *(const float4*)(rp + gc);
                } else {
                    float e[4];
                    #pragma unroll
                    for (int t = 0; t < 4; ++t) {
                        const int c = gc + t;
                        e[t] = ((unsigned)c < 512u) ? rp[c] : 0.f;
                    }
                    v = make_float4(e[0], e[1], e[2], e[3]);
                }
            }
            *(float4*)&raw[a][row][f4c << 2] = v;   // 16B aligned (208r+16f4c)
        }
    }
    __syncthreads();

    // ---- stage 2: horizontal convs of {x, y, x^2+y^2, xy} from LDS ----
    // 168 tasks = 42 rows x 4 col-groups; task (r,g) computes out col pairs
    // c = 4g+oc (v2f lanes = cols c, c+16), reading raw cols 4g..4g+35.
    if (tid < HR * 4) {
        const int r = tid >> 2;
        const int g = tid & 3;
        const float4* __restrict__ px = (const float4*)&raw[0][r][g << 2];
        const float4* __restrict__ py = (const float4*)&raw[1][r][g << 2];
        float4 X[9], Y[9];
        #pragma unroll
        for (int k = 0; k < 9; ++k) X[k] = px[k];
        #pragma unroll
        for (int k = 0; k < 9; ++k) Y[k] = py[k];
        float fx[36], fy[36];
        #pragma unroll
        for (int k = 0; k < 9; ++k) {
            fx[4*k+0] = X[k].x; fx[4*k+1] = X[k].y;
            fx[4*k+2] = X[k].z; fx[4*k+3] = X[k].w;
            fy[4*k+0] = Y[k].x; fy[4*k+1] = Y[k].y;
            fy[4*k+2] = Y[k].z; fy[4*k+3] = Y[k].w;
        }

        v2f acc[4][4];
        #pragma unroll
        for (int q = 0; q < 4; ++q)
            #pragma unroll
            for (int oc = 0; oc < 4; ++oc) acc[q][oc] = (v2f)0.f;

        #pragma unroll
        for (int k = 0; k < 14; ++k) {
            const v2f xv = (v2f){fx[3 + k], fx[19 + k]};
            const v2f yv = (v2f){fy[3 + k], fy[19 + k]};
            const v2f ss = xv * xv + yv * yv;
            const v2f xy = xv * yv;
            #pragma unroll
            for (int oc = 0; oc < 4; ++oc) {
                const int j = k - oc;            // compile-time
                if (j < 0 || j > 10) continue;
                const float wj = wk.w[j];
                acc[0][oc] += wj * xv;
                acc[1][oc] += wj * yv;
                acc[2][oc] += wj * ss;
                acc[3][oc] += wj * xy;
            }
        }
        #pragma unroll
        for (int q = 0; q < 4; ++q)
            #pragma unroll
            for (int oc = 0; oc < 4; ++oc)
                hst[q][((g << 2) + oc) * HR + r] = acc[q][oc];
    }
    __syncthreads();

    // ---- stage 3: vertical convs + SSIM; 128 tasks = 16 cp x 8 row-quads
    float lsum = 0.f;
    if (tid < 128) {
        const int cp = tid & 15;
        const int m0 = (tid >> 4) << 2;          // 0..28, output rows m0..m0+3
        v2f s[4][4];
        #pragma unroll
        for (int q = 0; q < 4; ++q) {
            const float4* __restrict__ p4 = (const float4*)&hst[q][cp * HR + m0];
            float4 Q[7];
            #pragma unroll
            for (int k = 0; k < 7; ++k) Q[k] = p4[k];   // h-rows m0..m0+13
            #pragma unroll
            for (int o = 0; o < 4; ++o) {
                v2f a = (v2f)0.f;
                #pragma unroll
                for (int j = 0; j < 11; ++j) {
                    const int t = o + j;                 // 0..13 compile-time
                    const v2f rv = (t & 1) ? (v2f){Q[t >> 1].z, Q[t >> 1].w}
                                           : (v2f){Q[t >> 1].x, Q[t >> 1].y};
                    a += wk.w[j] * rv;
                }
                s[q][o] = a;
            }
        }

        const float C1 = 1e-4f, C2 = 9e-4f;
        #pragma unroll
        for (int o = 0; o < 4; ++o) {
            const v2f mx = s[0][o], my = s[1][o];
            const v2f mx2 = mx * mx, my2 = my * my, mxy = mx * my;
            const v2f sig_sum = s[2][o] - mx2 - my2;   // sigma_x2 + sigma_y2
            const v2f sig_xy  = s[3][o] - mxy;
            const v2f num = (2.f * mxy + C1) * (2.f * sig_xy + C2);
            const v2f den = (mx2 + my2 + C1) * (sig_sum + C2) + 1e-12f;
            lsum += num.x * __builtin_amdgcn_rcpf(den.x)
                  + num.y * __builtin_amdgcn_rcpf(den.y);
        }
    }

    // ---- block reduction (4 waves) ----
    #pragma unroll
    for (int off = 32; off; off >>= 1) lsum += __shfl_down(lsum, off);
    if ((tid & 63) == 0) red[tid >> 6] = lsum;
    __syncthreads();
    if (tid == 0) {
        const float v = red[0] + red[1] + red[2] + red[3];
        if (atomic_mode) atomicAdd(partial, v);
        else partial[(bz * GY + by) * GX + bx] = v;
    }
}

__global__ __launch_bounds__(1024) void ssim_fin(const float* __restrict__ partial,
                                                 float* __restrict__ out, int n)
{
    float s = 0.f;
    for (int i = threadIdx.x; i < n; i += 1024) s += partial[i];
    #pragma unroll
    for (int off = 32; off; off >>= 1) s += __shfl_down(s, off);
    __shared__ float red[16];
    if ((threadIdx.x & 63) == 0) red[threadIdx.x >> 6] = s;
    __syncthreads();
    if (threadIdx.x == 0) {
        float v = 0.f;
        #pragma unroll
        for (int i = 0; i < 16; ++i) v += red[i];
        out[0] = 1.0f - v * (1.0f / 16777216.0f);
    }
}

extern "C" void kernel_launch(void* const* d_in, const int* in_sizes, int n_in,
                              void* d_out, int out_size, void* d_ws, size_t ws_size,
                              hipStream_t stream) {
    const float* x = (const float*)d_in[0];
    const float* y = (const float*)d_in[1];
    float* out = (float*)d_out;
    float* ws  = (float*)d_ws;

    W11 wk;
    double e[11], s = 0.0;
    for (int i = 0; i < 11; ++i) {
        double d = (double)i - 5.0;
        e[i] = exp(-(d * d) / 4.5);
        s += e[i];
    }
    for (int i = 0; i < 11; ++i) wk.w[i] = (float)(e[i] / s);

    const bool use_partial = ws_size >= (size_t)NPART * sizeof(float);
    if (!use_partial) hipMemsetAsync(d_ws, 0, sizeof(float), stream);

    hipLaunchKernelGGL(ssim_main, dim3(GX, GY, 64), dim3(256), 0, stream,
                       x, y, ws, wk, use_partial ? 0 : 1);
    hipLaunchKernelGGL(ssim_fin, dim3(1), dim3(1024), 0, stream,
                       ws, out, use_partial ? NPART : 1);
}

// Round 5
// 231.760 us; speedup vs baseline: 1.4794x; 1.0215x over previous
//
#include <hip/hip_runtime.h>
#include <math.h>

// SSIM loss fp32, B=64 H=W=512, 11x11 Gaussian sigma=1.5, separable (w ⊗ w).
// R13 = R11 resubmit #2 (two consecutive container infra failures; kernel
// re-audited for OOB/hang — none; R10->R11 delta is two constants).
// R11 = R10 + bank-conflict elimination + full stage-3 utilization.
// R10 counters: dur 136us, VALUBusy 41%, SQ_LDS_BANK_CONFLICT 21.9M
// (~86k cyc/CU = 26% of dispatch). Audit: raw stride 52 (≡20 mod 32) made
// staging writes AND stage-2 reads 2-way conflicted. Fix: stride 48
// (≡16 mod 32) -> stage-2 read phases cover all 32 banks exactly once
// (r even: {0,4,8,12}, r odd: {16,20,24,28}); staging writes are contiguous
// f4 (12/row at stride 12) -> conflict-free by construction. hst stride 42
// v2f (84 fl ≡ 20 mod 32) verified perfect for stage-3 b128 reads; kept.
// Stage 3: 256 threads x 2 rows (was 128 x 4) -> no idle waves, no guard.

typedef float v2f __attribute__((ext_vector_type(2)));

#define TSY  32                  // output rows per block
#define HR   42                  // h-rows = TSY + 10
#define RAWS 48                  // raw row stride floats (48 = 16 mod 32)
#define GX   16
#define GY   16
#define NPART (64 * GY * GX)     // 16384

struct W11 { float w[11]; };

__global__ __launch_bounds__(256, 4) void ssim_main(
    const float* __restrict__ x, const float* __restrict__ y,
    float* __restrict__ partial, W11 wk, int atomic_mode)
{
    // raw[a][r][c]: zero-padded input tile, a=0:x a=1:y.
    // raw col c <-> global col ox-8+c, c in 0..47; r <-> global row oy-5+r.
    __shared__ __align__(16) float raw[2][HR][RAWS];        // 16128 B
    // hst[q][cp*HR + r]: v2f = h-conv at (col ox+cp, col ox+cp+16).
    __shared__ __align__(16) v2f hst[4][16 * HR];           // 21504 B
    __shared__ float red[4];

    const int tid = threadIdx.x;
    const int bx = blockIdx.x, by = blockIdx.y, bz = blockIdx.z;
    const float* __restrict__ xb = x + (size_t)bz * (512 * 512);
    const float* __restrict__ yb = y + (size_t)bz * (512 * 512);
    const int ox = bx * 32;
    const int oy = by * TSY;

    // ---- stage 1: coalesced global -> LDS raw staging (zero-padded) ----
    // 1008 f4 tasks = 2 arrays x 42 rows x 12 f4; dst is flat-contiguous
    // (f4 index == task index) -> writes conflict-free.
    #pragma unroll
    for (int it = 0; it < 4; ++it) {
        const int i = tid + (it << 8);
        if (i < 1008) {
            const int a   = (i >= 504) ? 1 : 0;
            const int j   = i - a * 504;
            const int row = j / 12;          // 0..41 (magic-mul)
            const int f4c = j - row * 12;    // 0..11
            const int gr  = oy - 5 + row;
            const int gc  = ox - 8 + (f4c << 2);
            const float* __restrict__ sb = a ? yb : xb;
            float4 v = {0.f, 0.f, 0.f, 0.f};
            if ((unsigned)gr < 512u) {
                const float* __restrict__ rp = sb + gr * 512;
                if ((unsigned)gc <= 508u) {  // uniform-true for bx 1..14
                    v = *(const float4*)(rp + gc);
                } else {
                    float e[4];
                    #pragma unroll
                    for (int t = 0; t < 4; ++t) {
                        const int c = gc + t;
                        e[t] = ((unsigned)c < 512u) ? rp[c] : 0.f;
                    }
                    v = make_float4(e[0], e[1], e[2], e[3]);
                }
            }
            ((float4*)raw)[i] = v;
        }
    }
    __syncthreads();

    // ---- stage 2: horizontal convs of {x, y, x^2+y^2, xy} from LDS ----
    // 168 tasks = 42 rows x 4 col-groups; task (r,g) computes out col pairs
    // c = 4g+oc (v2f lanes = cols c, c+16), reading raw f4 g..g+8.
    if (tid < HR * 4) {
        const int r = tid >> 2;
        const int g = tid & 3;
        const float4* __restrict__ px = (const float4*)&raw[0][r][g << 2];
        const float4* __restrict__ py = (const float4*)&raw[1][r][g << 2];
        float4 X[9], Y[9];
        #pragma unroll
        for (int k = 0; k < 9; ++k) X[k] = px[k];
        #pragma unroll
        for (int k = 0; k < 9; ++k) Y[k] = py[k];
        float fx[36], fy[36];
        #pragma unroll
        for (int k = 0; k < 9; ++k) {
            fx[4*k+0] = X[k].x; fx[4*k+1] = X[k].y;
            fx[4*k+2] = X[k].z; fx[4*k+3] = X[k].w;
            fy[4*k+0] = Y[k].x; fy[4*k+1] = Y[k].y;
            fy[4*k+2] = Y[k].z; fy[4*k+3] = Y[k].w;
        }

        v2f acc[4][4];
        #pragma unroll
        for (int q = 0; q < 4; ++q)
            #pragma unroll
            for (int oc = 0; oc < 4; ++oc) acc[q][oc] = (v2f)0.f;

        #pragma unroll
        for (int k = 0; k < 14; ++k) {
            const v2f xv = (v2f){fx[3 + k], fx[19 + k]};
            const v2f yv = (v2f){fy[3 + k], fy[19 + k]};
            const v2f ss = xv * xv + yv * yv;
            const v2f xy = xv * yv;
            #pragma unroll
            for (int oc = 0; oc < 4; ++oc) {
                const int j = k - oc;            // compile-time
                if (j < 0 || j > 10) continue;
                const float wj = wk.w[j];
                acc[0][oc] += wj * xv;
                acc[1][oc] += wj * yv;
                acc[2][oc] += wj * ss;
                acc[3][oc] += wj * xy;
            }
        }
        #pragma unroll
        for (int q = 0; q < 4; ++q)
            #pragma unroll
            for (int oc = 0; oc < 4; ++oc)
                hst[q][((g << 2) + oc) * HR + r] = acc[q][oc];
    }
    __syncthreads();

    // ---- stage 3: vertical convs + SSIM; 256 tasks = 16 cp x 16 row-pairs
    // reads: b128 starts (84*cp + 4*rp) mod 32 cycle {0,20,8,28,16,4,24,12}
    // x 4 banks -> every 8-lane phase covers all 32 banks: conflict-free.
    const int cp = tid & 15;
    const int m0 = (tid >> 4) << 1;              // output rows m0, m0+1
    float lsum = 0.f;
    {
        v2f s[4][2];
        #pragma unroll
        for (int q = 0; q < 4; ++q) {
            const float4* __restrict__ p4 = (const float4*)&hst[q][cp * HR + m0];
            float4 Q[6];
            #pragma unroll
            for (int k = 0; k < 6; ++k) Q[k] = p4[k];   // h-rows m0..m0+11
            #pragma unroll
            for (int o = 0; o < 2; ++o) {
                v2f a = (v2f)0.f;
                #pragma unroll
                for (int j = 0; j < 11; ++j) {
                    const int t = o + j;                 // 0..11 compile-time
                    const v2f rv = (t & 1) ? (v2f){Q[t >> 1].z, Q[t >> 1].w}
                                           : (v2f){Q[t >> 1].x, Q[t >> 1].y};
                    a += wk.w[j] * rv;
                }
                s[q][o] = a;
            }
        }

        const float C1 = 1e-4f, C2 = 9e-4f;
        #pragma unroll
        for (int o = 0; o < 2; ++o) {
            const v2f mx = s[0][o], my = s[1][o];
            const v2f mx2 = mx * mx, my2 = my * my, mxy = mx * my;
            const v2f sig_sum = s[2][o] - mx2 - my2;   // sigma_x2 + sigma_y2
            const v2f sig_xy  = s[3][o] - mxy;
            const v2f num = (2.f * mxy + C1) * (2.f * sig_xy + C2);
            const v2f den = (mx2 + my2 + C1) * (sig_sum + C2) + 1e-12f;
            lsum += num.x * __builtin_amdgcn_rcpf(den.x)
                  + num.y * __builtin_amdgcn_rcpf(den.y);
        }
    }

    // ---- block reduction (4 waves) ----
    #pragma unroll
    for (int off = 32; off; off >>= 1) lsum += __shfl_down(lsum, off);
    if ((tid & 63) == 0) red[tid >> 6] = lsum;
    __syncthreads();
    if (tid == 0) {
        const float v = red[0] + red[1] + red[2] + red[3];
        if (atomic_mode) atomicAdd(partial, v);
        else partial[(bz * GY + by) * GX + bx] = v;
    }
}

__global__ __launch_bounds__(1024) void ssim_fin(const float* __restrict__ partial,
                                                 float* __restrict__ out, int n)
{
    float s = 0.f;
    for (int i = threadIdx.x; i < n; i += 1024) s += partial[i];
    #pragma unroll
    for (int off = 32; off; off >>= 1) s += __shfl_down(s, off);
    __shared__ float red[16];
    if ((threadIdx.x & 63) == 0) red[threadIdx.x >> 6] = s;
    __syncthreads();
    if (threadIdx.x == 0) {
        float v = 0.f;
        #pragma unroll
        for (int i = 0; i < 16; ++i) v += red[i];
        out[0] = 1.0f - v * (1.0f / 16777216.0f);
    }
}

extern "C" void kernel_launch(void* const* d_in, const int* in_sizes, int n_in,
                              void* d_out, int out_size, void* d_ws, size_t ws_size,
                              hipStream_t stream) {
    const float* x = (const float*)d_in[0];
    const float* y = (const float*)d_in[1];
    float* out = (float*)d_out;
    float* ws  = (float*)d_ws;

    W11 wk;
    double e[11], s = 0.0;
    for (int i = 0; i < 11; ++i) {
        double d = (double)i - 5.0;
        e[i] = exp(-(d * d) / 4.5);
        s += e[i];
    }
    for (int i = 0; i < 11; ++i) wk.w[i] = (float)(e[i] / s);

    const bool use_partial = ws_size >= (size_t)NPART * sizeof(float);
    if (!use_partial) hipMemsetAsync(d_ws, 0, sizeof(float), stream);

    hipLaunchKernelGGL(ssim_main, dim3(GX, GY, 64), dim3(256), 0, stream,
                       x, y, ws, wk, use_partial ? 0 : 1);
    hipLaunchKernelGGL(ssim_fin, dim3(1), dim3(1024), 0, stream,
                       ws, out, use_partial ? NPART : 1);
}